// Round 4
// baseline (5093.262 us; speedup 1.0000x reference)
//
#include <hip/hip_runtime.h>

// ATAE-LSTM fused pipeline for MI355X (gfx950).
// V=50000, D=512, B=64, L=512, A=4, 4D=2048.

using f32x4  = __attribute__((ext_vector_type(4))) float;
using s16x4  = __attribute__((ext_vector_type(4))) short;
using bf16x8 = __attribute__((ext_vector_type(8))) __bf16;

#define LOG2E 1.4426950408889634f

__device__ __forceinline__ float b2f(short s) {
  union { unsigned u; float f; } c;
  c.u = ((unsigned)(unsigned short)s) << 16;
  return c.f;
}
__device__ __forceinline__ short f2bf(float f) {
  union { float f; unsigned u; } c; c.f = f;
  unsigned r = (c.u + 0x7FFFu + ((c.u >> 16) & 1u)) >> 16;
  return (short)(unsigned short)r;
}
__device__ __forceinline__ float sigm_(float x) {
  float e = __builtin_amdgcn_exp2f(-x * LOG2E);
  return __builtin_amdgcn_rcpf(1.0f + e);
}
__device__ __forceinline__ float tanh_(float x) {
  float e = __builtin_amdgcn_exp2f(x * (2.0f * LOG2E));
  return 1.0f - 2.0f * __builtin_amdgcn_rcpf(1.0f + e);
}

// ---------------------------------------------------------------------------
// K1a: aspect embedding average; also zeroes hbuf (tags must start at 0 for
// every launch -> graph-replay deterministic).
__global__ void k_asp(const int* __restrict__ aspect, const int* __restrict__ alen,
                      const float* __restrict__ emb, float* __restrict__ asp_emb,
                      float* __restrict__ out_asp, unsigned* __restrict__ hbuf) {
  int b = blockIdx.x;          // 64
  int t = threadIdx.x;         // 128, 4 floats each
  {
    unsigned* hz = hbuf + (size_t)(b * 128 + t) * 8;  // 8192 thr x 8 u32 = 256KB
    #pragma unroll
    for (int i = 0; i < 8; ++i) hz[i] = 0u;
  }
  f32x4 s = {0.f, 0.f, 0.f, 0.f};
  #pragma unroll
  for (int a = 0; a < 4; ++a) {
    int idx = aspect[b * 4 + a];
    s += *(const f32x4*)(emb + (size_t)idx * 512 + t * 4);
  }
  float inv = 1.0f / (float)alen[b];
  s[0] *= inv; s[1] *= inv; s[2] *= inv; s[3] *= inv;
  *(f32x4*)(asp_emb + (size_t)b * 512 + t * 4) = s;
  *(f32x4*)(out_asp + (size_t)b * 512 + t * 4) = s;
}

// ---------------------------------------------------------------------------
// K1b: pack W_ih (word half) and W_hh rows into block-interleaved gate order,
// bf16.  Packed row P: j=P>>5 (block), u=(P>>2)&7 (unit), gate=P&3;
// source gate row gr = gate*512 + j*8 + u.  K-columns identity (unit order).
__global__ void k_pack(const float* __restrict__ W_ih, const float* __restrict__ W_hh,
                       short* __restrict__ W1p, short* __restrict__ Whp) {
  int P = blockIdx.x;          // 2048
  int t = threadIdx.x;         // 128, 4 elems each
  int gr = (P & 3) * 512 + (P >> 5) * 8 + ((P >> 2) & 7);
  f32x4 w1 = *(const f32x4*)(W_ih + (size_t)gr * 1024 + t * 4);
  f32x4 wh = *(const f32x4*)(W_hh + (size_t)gr * 512 + t * 4);
  s16x4 o1, oh;
  #pragma unroll
  for (int i = 0; i < 4; ++i) { o1[i] = f2bf(w1[i]); oh[i] = f2bf(wh[i]); }
  *(s16x4*)(W1p + (size_t)P * 512 + t * 4) = o1;
  *(s16x4*)(Whp + (size_t)P * 512 + t * 4) = oh;
}

// ---------------------------------------------------------------------------
// K1c: asp_contrib[b][P] = asp_emb[b] . W_ih[gr][512:1024] + b_ih[gr] + b_hh[gr]
__global__ void k_aspc(const float* __restrict__ asp_emb, const float* __restrict__ W_ih,
                       const float* __restrict__ b_ih, const float* __restrict__ b_hh,
                       float* __restrict__ aspc) {
  int tid = threadIdx.x;                 // 256
  int P = blockIdx.x * 32 + (tid >> 3);  // 64 blocks
  int gr = (P & 3) * 512 + (P >> 5) * 8 + ((P >> 2) & 7);
  const float* wrow = W_ih + (size_t)gr * 1024 + 512;
  float bias = b_ih[gr] + b_hh[gr];
  int b0 = (tid & 7) * 8;
  float a[8];
  #pragma unroll
  for (int i = 0; i < 8; ++i) a[i] = 0.f;
  for (int k = 0; k < 512; k += 4) {
    f32x4 wv = *(const f32x4*)(wrow + k);
    #pragma unroll
    for (int bb = 0; bb < 8; ++bb) {
      f32x4 av = *(const f32x4*)(asp_emb + (size_t)(b0 + bb) * 512 + k);
      a[bb] += wv[0] * av[0] + wv[1] * av[1] + wv[2] * av[2] + wv[3] * av[3];
    }
  }
  #pragma unroll
  for (int bb = 0; bb < 8; ++bb) aspc[(size_t)(b0 + bb) * 2048 + P] = a[bb] + bias;
}

// ---------------------------------------------------------------------------
// K2: word embedding gather -> bf16, zero masked rows.
__global__ void k_gather(const int* __restrict__ X, const int* __restrict__ xlen,
                         const float* __restrict__ emb, short* __restrict__ word) {
  int g = blockIdx.x * 256 + threadIdx.x;  // 16384 blocks
  int row = g >> 7;                        // 128 threads per row
  int k4 = (g & 127) << 2;
  int b = row >> 9, l = row & 511;
  s16x4 o;
  if (l < xlen[b]) {
    int idx = X[row];
    f32x4 v = *(const f32x4*)(emb + (size_t)idx * 512 + k4);
    o[0] = f2bf(v[0]); o[1] = f2bf(v[1]); o[2] = f2bf(v[2]); o[3] = f2bf(v[3]);
  } else {
    o[0] = 0; o[1] = 0; o[2] = 0; o[3] = 0;
  }
  *(s16x4*)(word + (size_t)row * 512 + k4) = o;
}

// ---------------------------------------------------------------------------
// K3: GEMM  xproj[(b,l)][P] = word[(b,l),:] . W1p[P,:] + aspc[b][P]   (bf16 out)
__global__ __launch_bounds__(256)
void k_gemm(const short* __restrict__ A, const short* __restrict__ B,
            const float* __restrict__ aspc, const int* __restrict__ xlen,
            short* __restrict__ C) {
  __shared__ char smem[65536];  // A0 A1 B0 B1, 16KB each
  const int rt = blockIdx.x, ct = blockIdx.y;
  const int b = rt >> 2;
  if (xlen[b] <= ((rt & 3) << 7)) return;  // fully-masked row tile
  const int tid = threadIdx.x;
  const int w = tid >> 6, lane = tid & 63;
  const int lr = lane & 15, lg = lane >> 4;
  const int wr = (w & 1) * 64, wc = (w >> 1) * 64;
  const char* Ab = (const char*)(A + (size_t)rt * 128 * 512);
  const char* Bb = (const char*)(B + (size_t)ct * 128 * 512);

  f32x4 acc[4][4];
  #pragma unroll
  for (int mi = 0; mi < 4; ++mi)
    #pragma unroll
    for (int ni = 0; ni < 4; ++ni) acc[mi][ni] = {0.f, 0.f, 0.f, 0.f};

  auto stage = [&](int kt, int buf) {
    #pragma unroll
    for (int p = 0; p < 4; ++p) {
      int dbase = w * 1024 + p * 4096;   // wave-uniform LDS base
      int d = dbase + (lane << 4);
      int row = d >> 7;
      int kb = (d & 127) ^ (((d >> 9) & 1) << 5);  // pre-swizzled source
      __builtin_amdgcn_global_load_lds(
          (const __attribute__((address_space(1))) unsigned*)(Ab + (size_t)row * 1024 + kt * 128 + kb),
          (__attribute__((address_space(3))) unsigned*)(smem + buf * 16384 + dbase), 16, 0, 0);
      __builtin_amdgcn_global_load_lds(
          (const __attribute__((address_space(1))) unsigned*)(Bb + (size_t)row * 1024 + kt * 128 + kb),
          (__attribute__((address_space(3))) unsigned*)(smem + 32768 + buf * 16384 + dbase), 16, 0, 0);
    }
  };

  stage(0, 0);
  __syncthreads();
  #pragma unroll 1
  for (int kt = 0; kt < 8; ++kt) {
    int cur = kt & 1;
    if (kt < 7) stage(kt + 1, cur ^ 1);
    const char* sAc = smem + cur * 16384;
    const char* sBc = smem + 32768 + cur * 16384;
    #pragma unroll
    for (int kk = 0; kk < 2; ++kk) {
      bf16x8 af[4], bfr[4];
      #pragma unroll
      for (int mi = 0; mi < 4; ++mi) {
        int lin = (wr + mi * 16 + lr) * 128 + kk * 64 + lg * 16;
        af[mi] = *(const bf16x8*)(sAc + (lin ^ (((lin >> 9) & 1) << 5)));
      }
      #pragma unroll
      for (int ni = 0; ni < 4; ++ni) {
        int lin = (wc + ni * 16 + lr) * 128 + kk * 64 + lg * 16;
        bfr[ni] = *(const bf16x8*)(sBc + (lin ^ (((lin >> 9) & 1) << 5)));
      }
      #pragma unroll
      for (int mi = 0; mi < 4; ++mi)
        #pragma unroll
        for (int ni = 0; ni < 4; ++ni)
          acc[mi][ni] = __builtin_amdgcn_mfma_f32_16x16x32_bf16(af[mi], bfr[ni], acc[mi][ni], 0, 0, 0);
    }
    __syncthreads();
  }

  const int colb = ct * 128 + wc;
  float cb[4];
  #pragma unroll
  for (int ni = 0; ni < 4; ++ni) cb[ni] = aspc[(size_t)b * 2048 + colb + ni * 16 + lr];
  #pragma unroll
  for (int mi = 0; mi < 4; ++mi) {
    const int row0 = rt * 128 + wr + mi * 16 + lg * 4;
    #pragma unroll
    for (int r = 0; r < 4; ++r) {
      short* crow = C + (size_t)(row0 + r) * 2048 + colb + lr;
      #pragma unroll
      for (int ni = 0; ni < 4; ++ni)
        crow[ni * 16] = f2bf(acc[mi][ni][r] + cb[ni]);
    }
  }
}

// ---------------------------------------------------------------------------
// K4: persistent LSTM recurrence, self-tagged h exchange through L3.
// Published dword = (bf16(h) << 16) | (t+1).  Two-phase consume:
//   phase 1: 4B sentinel polls (8x lighter fabric traffic than full lines)
//   phase 2: bulk 32B-line read, every dword tag-validated (correctness anchor)
// Long-latency ops (out stores, x prefetch) are issued AFTER the probe so no
// probe vmcnt(0) ever drains them; out stores are deferred one step.
__global__ __launch_bounds__(256, 1)
void k_rnn(const short* __restrict__ xproj, const short* __restrict__ Whp,
           const int* __restrict__ xlen, unsigned* hbuf, float* __restrict__ out) {
  __shared__ char wlds[32768];
  const int j = blockIdx.x;       // 64
  const int tid = threadIdx.x;
  const int w = tid >> 6;
  const int lane = tid & 63;
  const int lr = lane & 15, lg = lane >> 4;
  const int batch = w * 16 + lr;
  const int mylen = xlen[batch];

  // block-uniform max sequence length
  int nt = xlen[lane];
  #pragma unroll
  for (int d = 32; d; d >>= 1) nt = max(nt, __shfl_xor(nt, d));

  // stage this block's W_hh slice (32 rows x 512 cols bf16 = 32KB) into LDS,
  // XOR-swizzled (row&7)<<4 against the stride-1024 bank conflict.
  {
    const char* src = (const char*)(Whp + (size_t)j * 32 * 512);
    int base = tid * 128;
    int row = base >> 10;
    int c0 = base & 1023;
    #pragma unroll
    for (int i = 0; i < 8; ++i) {
      int c = c0 + i * 16;
      *(f32x4*)(wlds + row * 1024 + (c ^ ((row & 7) << 4))) =
          *(const f32x4*)(src + (size_t)row * 1024 + c);
    }
  }
  __syncthreads();

  float cc0 = 0.f, cc1 = 0.f, h0 = 0.f, h1 = 0.f;
  float po0 = 0.f, po1 = 0.f;           // deferred out values (step t-1)
  const short* xbase = xproj + (size_t)batch * 512 * 2048 + j * 32 + lg * 4;
  float* outb = out + (size_t)batch * 512 * 512 + (size_t)j * 8 + lg;

  s16x4 xc0 = *(const s16x4*)(xbase);         // x(t), starts at t=0
  s16x4 xc1 = *(const s16x4*)(xbase + 16);
  s16x4 xn0 = xc0, xn1 = xc1;

  #pragma unroll 1
  for (int t = 0; t < nt; ++t) {
    f32x4 acc0 = {0.f, 0.f, 0.f, 0.f}, acc1 = {0.f, 0.f, 0.f, 0.f};
    if (t > 0) {
      const unsigned* hbL = hbuf + (size_t)((t - 1) & 1) * 32768 + batch * 512;
      const unsigned tneed = (unsigned)t;   // tag written at step t-1 is t
      // ---- phase 1: sentinel polling (4B per group per lane)
      {
        int sv[16];
        unsigned pend = 0xffffu;
        while (pend) {
          #pragma unroll
          for (int kk = 0; kk < 16; ++kk)
            if (pend & (1u << kk)) {
              const unsigned* p = hbL + kk * 32 + lg * 8 + (lr & 7);
              asm volatile("global_load_dword %0, %1, off sc0 sc1"
                           : "=&v"(sv[kk]) : "v"(p) : "memory");
            }
          asm volatile("s_waitcnt vmcnt(0)" ::: "memory");
          __builtin_amdgcn_sched_barrier(0);
          #pragma unroll
          for (int kk = 0; kk < 16; ++kk)
            if (pend & (1u << kk))
              if (__all(((unsigned)sv[kk] & 0xffffu) >= tneed)) pend &= ~(1u << kk);
        }
      }
      // ---- phase 2: bulk read, full per-dword tag validation
      bf16x8 Bf[16];
      {
        int4 ta[16], tb[16];
        unsigned pend = 0xffffu;
        while (pend) {
          #pragma unroll
          for (int kk = 0; kk < 16; ++kk)
            if (pend & (1u << kk)) {
              const unsigned* p = hbL + kk * 32 + lg * 8;
              asm volatile("global_load_dwordx4 %0, %1, off sc0 sc1"
                           : "=&v"(ta[kk]) : "v"(p) : "memory");
              asm volatile("global_load_dwordx4 %0, %1, off sc0 sc1"
                           : "=&v"(tb[kk]) : "v"(p + 4) : "memory");
            }
          asm volatile("s_waitcnt vmcnt(0)" ::: "memory");
          __builtin_amdgcn_sched_barrier(0);
          #pragma unroll
          for (int kk = 0; kk < 16; ++kk)
            if (pend & (1u << kk)) {
              int4 q0 = ta[kk], q1 = tb[kk];
              unsigned m0 = min((unsigned)q0.x & 0xffffu, (unsigned)q0.y & 0xffffu);
              unsigned m1 = min((unsigned)q0.z & 0xffffu, (unsigned)q0.w & 0xffffu);
              unsigned m2 = min((unsigned)q1.x & 0xffffu, (unsigned)q1.y & 0xffffu);
              unsigned m3 = min((unsigned)q1.z & 0xffffu, (unsigned)q1.w & 0xffffu);
              unsigned mn = min(min(m0, m1), min(m2, m3));
              if (__all(mn >= tneed)) {
                union { unsigned u[4]; bf16x8 v; } pk;
                pk.u[0] = ((unsigned)q0.x >> 16) | ((unsigned)q0.y & 0xffff0000u);
                pk.u[1] = ((unsigned)q0.z >> 16) | ((unsigned)q0.w & 0xffff0000u);
                pk.u[2] = ((unsigned)q1.x >> 16) | ((unsigned)q1.y & 0xffff0000u);
                pk.u[3] = ((unsigned)q1.z >> 16) | ((unsigned)q1.w & 0xffff0000u);
                Bf[kk] = pk.v;
                pend &= ~(1u << kk);
              }
            }
        }
      }
      // deferred out-store (step t-1) + x(t+1) prefetch: issued here so they
      // have a full step before any vmcnt(0) can see them.
      outb[(size_t)(t - 1) * 512] = po0;
      outb[(size_t)(t - 1) * 512 + 4] = po1;
      if (t + 1 < nt) {
        const short* xp = xbase + (size_t)(t + 1) * 2048;
        xn0 = *(const s16x4*)(xp);
        xn1 = *(const s16x4*)(xp + 16);
      }
      // MFMA: gates += W_hh . h(t-1)
      #pragma unroll
      for (int kk = 0; kk < 16; ++kk) {
        int sw = (kk * 64 + lg * 16) ^ ((lr & 7) << 4);
        bf16x8 a0 = *(const bf16x8*)(wlds + lr * 1024 + sw);
        bf16x8 a1 = *(const bf16x8*)(wlds + (16 + lr) * 1024 + sw);
        acc0 = __builtin_amdgcn_mfma_f32_16x16x32_bf16(a0, Bf[kk], acc0, 0, 0, 0);
        acc1 = __builtin_amdgcn_mfma_f32_16x16x32_bf16(a1, Bf[kk], acc1, 0, 0, 0);
      }
    } else {
      if (nt > 1) {
        const short* xp = xbase + 2048;
        xn0 = *(const s16x4*)(xp);
        xn1 = *(const s16x4*)(xp + 16);
      }
    }

    const bool m = (t < mylen);
    float hn0, hn1;
    {  // mt = 0: unit = lg, regs = i,f,g,o
      float gi = acc0[0] + b2f(xc0[0]);
      float gf = acc0[1] + b2f(xc0[1]);
      float gg = acc0[2] + b2f(xc0[2]);
      float go = acc0[3] + b2f(xc0[3]);
      float ii = sigm_(gi), ff = sigm_(gf), gv = tanh_(gg), oo = sigm_(go);
      float cn = ff * cc0 + ii * gv;
      hn0 = oo * tanh_(cn);
      cc0 = m ? cn : cc0;
      h0 = m ? hn0 : h0;
    }
    {  // mt = 1: unit = 4 + lg
      float gi = acc1[0] + b2f(xc1[0]);
      float gf = acc1[1] + b2f(xc1[1]);
      float gg = acc1[2] + b2f(xc1[2]);
      float go = acc1[3] + b2f(xc1[3]);
      float ii = sigm_(gi), ff = sigm_(gf), gv = tanh_(gg), oo = sigm_(go);
      float cn = ff * cc1 + ii * gv;
      hn1 = oo * tanh_(cn);
      cc1 = m ? cn : cc1;
      h1 = m ? hn1 : h1;
    }

    // fire-and-forget tagged publish (critical path: right after gate math)
    unsigned tag = (unsigned)(t + 1) & 0xffffu;
    unsigned d0 = ((unsigned)(unsigned short)f2bf(h0) << 16) | tag;
    unsigned d1 = ((unsigned)(unsigned short)f2bf(h1) << 16) | tag;
    unsigned* hw = hbuf + (size_t)(t & 1) * 32768 + batch * 512 + j * 8 + lg;
    __hip_atomic_store(hw, d0, __ATOMIC_RELAXED, __HIP_MEMORY_SCOPE_AGENT);
    __hip_atomic_store(hw + 4, d1, __ATOMIC_RELAXED, __HIP_MEMORY_SCOPE_AGENT);

    // stage out(t) for deferred store; rotate x
    po0 = m ? hn0 : 0.0f;
    po1 = m ? hn1 : 0.0f;
    xc0 = xn0; xc1 = xn1;
  }

  // final deferred out-store (step nt-1)
  outb[(size_t)(nt - 1) * 512] = po0;
  outb[(size_t)(nt - 1) * 512 + 4] = po1;

  // zero tail of the sequence output (t >= nt >= all xlen)
  for (int t = nt; t < 512; ++t) {
    outb[(size_t)t * 512] = 0.0f;
    outb[(size_t)t * 512 + 4] = 0.0f;
  }

  // final hidden state hT -> out[B*L*D + batch*512 + hid]
  float* oh = out + (size_t)64 * 512 * 512 + (size_t)batch * 512 + j * 8;
  oh[lg] = h0;
  oh[4 + lg] = h1;
}

// ---------------------------------------------------------------------------
extern "C" void kernel_launch(void* const* d_in, const int* in_sizes, int n_in,
                              void* d_out, int out_size, void* d_ws, size_t ws_size,
                              hipStream_t stream) {
  const int*   X      = (const int*)d_in[0];
  const int*   Xlen   = (const int*)d_in[1];
  const int*   aspect = (const int*)d_in[2];
  const int*   alen   = (const int*)d_in[3];
  const float* emb    = (const float*)d_in[4];
  const float* W_ih   = (const float*)d_in[5];
  const float* W_hh   = (const float*)d_in[6];
  const float* b_ih   = (const float*)d_in[7];
  const float* b_hh   = (const float*)d_in[8];
  float* out = (float*)d_out;

  char* ws = (char*)d_ws;
  // offsets (bytes)
  float*    asp_emb = (float*)(ws + 0);           //    131072
  float*    aspc    = (float*)(ws + 131072);      //    524288
  short*    W1p     = (short*)(ws + 655360);      //   2097152
  short*    Whp     = (short*)(ws + 2752512);     //   2097152
  unsigned* hbuf    = (unsigned*)(ws + 4849664);  //    262144 (2 gens x 32768 u32, tagged)
  short*    word    = (short*)(ws + 5111808);     //  33554432
  short*    xproj   = (short*)(ws + 38666240);    // 134217728  (total ~165MB)

  float* out_hT  = out + (size_t)64 * 512 * 512;            // (1,B,D)
  float* out_asp = out_hT + (size_t)64 * 512;               // (B,D)

  hipLaunchKernelGGL(k_asp,    dim3(64),        dim3(128), 0, stream,
                     aspect, alen, emb, asp_emb, out_asp, hbuf);
  hipLaunchKernelGGL(k_pack,   dim3(2048),      dim3(128), 0, stream,
                     W_ih, W_hh, W1p, Whp);
  hipLaunchKernelGGL(k_aspc,   dim3(64),        dim3(256), 0, stream,
                     asp_emb, W_ih, b_ih, b_hh, aspc);
  hipLaunchKernelGGL(k_gather, dim3(16384),     dim3(256), 0, stream,
                     X, Xlen, emb, word);
  hipLaunchKernelGGL(k_gemm,   dim3(256, 16),   dim3(256), 0, stream,
                     word, W1p, aspc, Xlen, xproj);
  hipLaunchKernelGGL(k_rnn,    dim3(64),        dim3(256), 0, stream,
                     xproj, Whp, Xlen, hbuf, out);
}

// Round 5
// 3459.892 us; speedup vs baseline: 1.4721x; 1.4721x over previous
//
#include <hip/hip_runtime.h>

// ATAE-LSTM fused pipeline for MI355X (gfx950).
// V=50000, D=512, B=64, L=512, A=4, 4D=2048.

using f32x4  = __attribute__((ext_vector_type(4))) float;
using s16x4  = __attribute__((ext_vector_type(4))) short;
using bf16x8 = __attribute__((ext_vector_type(8))) __bf16;

#define LOG2E 1.4426950408889634f

__device__ __forceinline__ float b2f(short s) {
  union { unsigned u; float f; } c;
  c.u = ((unsigned)(unsigned short)s) << 16;
  return c.f;
}
__device__ __forceinline__ short f2bf(float f) {
  union { float f; unsigned u; } c; c.f = f;
  unsigned r = (c.u + 0x7FFFu + ((c.u >> 16) & 1u)) >> 16;
  return (short)(unsigned short)r;
}
__device__ __forceinline__ float sigm_(float x) {
  float e = __builtin_amdgcn_exp2f(-x * LOG2E);
  return __builtin_amdgcn_rcpf(1.0f + e);
}
__device__ __forceinline__ float tanh_(float x) {
  float e = __builtin_amdgcn_exp2f(x * (2.0f * LOG2E));
  return 1.0f - 2.0f * __builtin_amdgcn_rcpf(1.0f + e);
}

// ---------------------------------------------------------------------------
// K1a: aspect embedding average; zeroes the 256 per-wave sync flags (fresh
// each launch -> graph-replay deterministic).
__global__ void k_asp(const int* __restrict__ aspect, const int* __restrict__ alen,
                      const float* __restrict__ emb, float* __restrict__ asp_emb,
                      float* __restrict__ out_asp, int* __restrict__ flags) {
  int b = blockIdx.x;          // 64
  int t = threadIdx.x;         // 128, 4 floats each
  if (b == 0) { flags[t] = 0; flags[128 + t] = 0; }
  f32x4 s = {0.f, 0.f, 0.f, 0.f};
  #pragma unroll
  for (int a = 0; a < 4; ++a) {
    int idx = aspect[b * 4 + a];
    s += *(const f32x4*)(emb + (size_t)idx * 512 + t * 4);
  }
  float inv = 1.0f / (float)alen[b];
  s[0] *= inv; s[1] *= inv; s[2] *= inv; s[3] *= inv;
  *(f32x4*)(asp_emb + (size_t)b * 512 + t * 4) = s;
  *(f32x4*)(out_asp + (size_t)b * 512 + t * 4) = s;
}

// ---------------------------------------------------------------------------
// K1b: pack W_ih (word half) and W_hh rows into block-interleaved gate order,
// bf16.  Packed row P: j=P>>5 (block), u=(P>>2)&7 (unit), gate=P&3;
// source gate row gr = gate*512 + j*8 + u.
// Whp ONLY: K-columns permuted within each 8-group (position c <- unit
// (c&1)*4 + (c>>1)&3) so a producer thread's (h_lg, h_{lg+4}) pair is one
// dword and the consumer's B-fragment K order matches (validated in R2).
__global__ void k_pack(const float* __restrict__ W_ih, const float* __restrict__ W_hh,
                       short* __restrict__ W1p, short* __restrict__ Whp) {
  int P = blockIdx.x;          // 2048
  int t = threadIdx.x;         // 128, 4 elems each
  int gr = (P & 3) * 512 + (P >> 5) * 8 + ((P >> 2) & 7);
  f32x4 w1 = *(const f32x4*)(W_ih + (size_t)gr * 1024 + t * 4);
  s16x4 o1, oh;
  #pragma unroll
  for (int i = 0; i < 4; ++i) {
    o1[i] = f2bf(w1[i]);
    int c = t * 4 + i;
    int ks = (c & ~7) | (((c & 1) << 2) | ((c >> 1) & 3));
    oh[i] = f2bf(W_hh[(size_t)gr * 512 + ks]);
  }
  *(s16x4*)(W1p + (size_t)P * 512 + t * 4) = o1;
  *(s16x4*)(Whp + (size_t)P * 512 + t * 4) = oh;
}

// ---------------------------------------------------------------------------
// K1c: asp_contrib[b][P] = asp_emb[b] . W_ih[gr][512:1024] + b_ih[gr] + b_hh[gr]
__global__ void k_aspc(const float* __restrict__ asp_emb, const float* __restrict__ W_ih,
                       const float* __restrict__ b_ih, const float* __restrict__ b_hh,
                       float* __restrict__ aspc) {
  int tid = threadIdx.x;                 // 256
  int P = blockIdx.x * 32 + (tid >> 3);  // 64 blocks
  int gr = (P & 3) * 512 + (P >> 5) * 8 + ((P >> 2) & 7);
  const float* wrow = W_ih + (size_t)gr * 1024 + 512;
  float bias = b_ih[gr] + b_hh[gr];
  int b0 = (tid & 7) * 8;
  float a[8];
  #pragma unroll
  for (int i = 0; i < 8; ++i) a[i] = 0.f;
  for (int k = 0; k < 512; k += 4) {
    f32x4 wv = *(const f32x4*)(wrow + k);
    #pragma unroll
    for (int bb = 0; bb < 8; ++bb) {
      f32x4 av = *(const f32x4*)(asp_emb + (size_t)(b0 + bb) * 512 + k);
      a[bb] += wv[0] * av[0] + wv[1] * av[1] + wv[2] * av[2] + wv[3] * av[3];
    }
  }
  #pragma unroll
  for (int bb = 0; bb < 8; ++bb) aspc[(size_t)(b0 + bb) * 2048 + P] = a[bb] + bias;
}

// ---------------------------------------------------------------------------
// K2: word embedding gather -> bf16, zero masked rows.
__global__ void k_gather(const int* __restrict__ X, const int* __restrict__ xlen,
                         const float* __restrict__ emb, short* __restrict__ word) {
  int g = blockIdx.x * 256 + threadIdx.x;  // 16384 blocks
  int row = g >> 7;                        // 128 threads per row
  int k4 = (g & 127) << 2;
  int b = row >> 9, l = row & 511;
  s16x4 o;
  if (l < xlen[b]) {
    int idx = X[row];
    f32x4 v = *(const f32x4*)(emb + (size_t)idx * 512 + k4);
    o[0] = f2bf(v[0]); o[1] = f2bf(v[1]); o[2] = f2bf(v[2]); o[3] = f2bf(v[3]);
  } else {
    o[0] = 0; o[1] = 0; o[2] = 0; o[3] = 0;
  }
  *(s16x4*)(word + (size_t)row * 512 + k4) = o;
}

// ---------------------------------------------------------------------------
// K3: GEMM  xproj[(b,l)][P] = word[(b,l),:] . W1p[P,:] + aspc[b][P]   (bf16 out)
__global__ __launch_bounds__(256)
void k_gemm(const short* __restrict__ A, const short* __restrict__ B,
            const float* __restrict__ aspc, const int* __restrict__ xlen,
            short* __restrict__ C) {
  __shared__ char smem[65536];  // A0 A1 B0 B1, 16KB each
  const int rt = blockIdx.x, ct = blockIdx.y;
  const int b = rt >> 2;
  if (xlen[b] <= ((rt & 3) << 7)) return;  // fully-masked row tile
  const int tid = threadIdx.x;
  const int w = tid >> 6, lane = tid & 63;
  const int lr = lane & 15, lg = lane >> 4;
  const int wr = (w & 1) * 64, wc = (w >> 1) * 64;
  const char* Ab = (const char*)(A + (size_t)rt * 128 * 512);
  const char* Bb = (const char*)(B + (size_t)ct * 128 * 512);

  f32x4 acc[4][4];
  #pragma unroll
  for (int mi = 0; mi < 4; ++mi)
    #pragma unroll
    for (int ni = 0; ni < 4; ++ni) acc[mi][ni] = {0.f, 0.f, 0.f, 0.f};

  auto stage = [&](int kt, int buf) {
    #pragma unroll
    for (int p = 0; p < 4; ++p) {
      int dbase = w * 1024 + p * 4096;   // wave-uniform LDS base
      int d = dbase + (lane << 4);
      int row = d >> 7;
      int kb = (d & 127) ^ (((d >> 9) & 1) << 5);  // pre-swizzled source
      __builtin_amdgcn_global_load_lds(
          (const __attribute__((address_space(1))) unsigned*)(Ab + (size_t)row * 1024 + kt * 128 + kb),
          (__attribute__((address_space(3))) unsigned*)(smem + buf * 16384 + dbase), 16, 0, 0);
      __builtin_amdgcn_global_load_lds(
          (const __attribute__((address_space(1))) unsigned*)(Bb + (size_t)row * 1024 + kt * 128 + kb),
          (__attribute__((address_space(3))) unsigned*)(smem + 32768 + buf * 16384 + dbase), 16, 0, 0);
    }
  };

  stage(0, 0);
  __syncthreads();
  #pragma unroll 1
  for (int kt = 0; kt < 8; ++kt) {
    int cur = kt & 1;
    if (kt < 7) stage(kt + 1, cur ^ 1);
    const char* sAc = smem + cur * 16384;
    const char* sBc = smem + 32768 + cur * 16384;
    #pragma unroll
    for (int kk = 0; kk < 2; ++kk) {
      bf16x8 af[4], bfr[4];
      #pragma unroll
      for (int mi = 0; mi < 4; ++mi) {
        int lin = (wr + mi * 16 + lr) * 128 + kk * 64 + lg * 16;
        af[mi] = *(const bf16x8*)(sAc + (lin ^ (((lin >> 9) & 1) << 5)));
      }
      #pragma unroll
      for (int ni = 0; ni < 4; ++ni) {
        int lin = (wc + ni * 16 + lr) * 128 + kk * 64 + lg * 16;
        bfr[ni] = *(const bf16x8*)(sBc + (lin ^ (((lin >> 9) & 1) << 5)));
      }
      #pragma unroll
      for (int mi = 0; mi < 4; ++mi)
        #pragma unroll
        for (int ni = 0; ni < 4; ++ni)
          acc[mi][ni] = __builtin_amdgcn_mfma_f32_16x16x32_bf16(af[mi], bfr[ni], acc[mi][ni], 0, 0, 0);
    }
    __syncthreads();
  }

  const int colb = ct * 128 + wc;
  float cb[4];
  #pragma unroll
  for (int ni = 0; ni < 4; ++ni) cb[ni] = aspc[(size_t)b * 2048 + colb + ni * 16 + lr];
  #pragma unroll
  for (int mi = 0; mi < 4; ++mi) {
    const int row0 = rt * 128 + wr + mi * 16 + lg * 4;
    #pragma unroll
    for (int r = 0; r < 4; ++r) {
      short* crow = C + (size_t)(row0 + r) * 2048 + colb + lr;
      #pragma unroll
      for (int ni = 0; ni < 4; ++ni)
        crow[ni * 16] = f2bf(acc[mi][ni][r] + cb[ni]);
    }
  }
}

// ---------------------------------------------------------------------------
// K4: persistent LSTM recurrence, flag-gated single-pass h exchange via L3.
// Producer wave: 1 packed u32 h-store/thread (sc0sc1) -> vmcnt(0) -> lane0
// flag store. Consumer wave w: polls its 64 producers' flags (1 dword/lane
// over a 256B region), then ONE untagged bulk pass (16x dwordx4/lane),
// guaranteed fresh by drain-before-flag ordering. No fences, no retries.
__global__ __launch_bounds__(256, 1)
void k_rnn(const short* __restrict__ xproj, const short* __restrict__ Whp,
           const int* __restrict__ xlen, unsigned* hbuf, int* flags,
           float* __restrict__ out) {
  __shared__ char wlds[32768];
  const int j = blockIdx.x;       // 64
  const int tid = threadIdx.x;
  const int w = tid >> 6;
  const int lane = tid & 63;
  const int lr = lane & 15, lg = lane >> 4;
  const int batch = w * 16 + lr;
  const int mylen = xlen[batch];

  // block-uniform max sequence length (identical in every block)
  int nt = xlen[lane];
  #pragma unroll
  for (int d = 32; d; d >>= 1) nt = max(nt, __shfl_xor(nt, d));

  // stage this block's W_hh slice (32 rows x 512 cols bf16 = 32KB) into LDS,
  // XOR-swizzled (row&7)<<4 against the stride-1024 bank conflict.
  {
    const char* src = (const char*)(Whp + (size_t)j * 32 * 512);
    int base = tid * 128;
    int row = base >> 10;
    int c0 = base & 1023;
    #pragma unroll
    for (int i = 0; i < 8; ++i) {
      int c = c0 + i * 16;
      *(f32x4*)(wlds + row * 1024 + (c ^ ((row & 7) << 4))) =
          *(const f32x4*)(src + (size_t)row * 1024 + c);
    }
  }
  __syncthreads();

  float cc0 = 0.f, cc1 = 0.f, h0 = 0.f, h1 = 0.f;
  const short* xbase = xproj + (size_t)batch * 512 * 2048 + j * 32 + lg * 4;
  float* outb = out + (size_t)batch * 512 * 512 + (size_t)j * 8 + lg;
  const int* fpoll = flags + w * 64 + lane;   // wave w needs only wave-w producers
  int* fmine = flags + w * 64 + j;

  s16x4 xc0 = *(const s16x4*)(xbase);         // x(t=0), mt=0 (i,f,g,o)
  s16x4 xc1 = *(const s16x4*)(xbase + 16);    // mt=1

  #pragma unroll 1
  for (int t = 0; t < nt; ++t) {
    f32x4 acc0 = {0.f, 0.f, 0.f, 0.f}, acc1 = {0.f, 0.f, 0.f, 0.f};
    if (t > 0) {
      // ---- poll: my 64 producers published gen t-1?  (1 dword/lane/pass)
      while (true) {
        int fv;
        asm volatile("global_load_dword %0, %1, off sc0 sc1"
                     : "=&v"(fv) : "v"(fpoll) : "memory");
        asm volatile("s_waitcnt vmcnt(0)" ::: "memory");
        if (__all((unsigned)fv >= (unsigned)t)) break;
      }
      __builtin_amdgcn_sched_barrier(0);
      // ---- single bulk pass: h(t-1) for my batch (guaranteed fresh)
      const char* hbL = (const char*)(hbuf + (size_t)((t - 1) & 1) * 16384)
                        + batch * 1024 + lg * 16;
      int4 hq[16];
      #pragma unroll
      for (int kk = 0; kk < 16; ++kk)
        asm volatile("global_load_dwordx4 %0, %1, off sc0 sc1"
                     : "=&v"(hq[kk]) : "v"(hbL + kk * 64) : "memory");
      asm volatile("s_waitcnt vmcnt(0)" ::: "memory");
      __builtin_amdgcn_sched_barrier(0);
      // ---- MFMA: gates += W_hh . h(t-1)
      #pragma unroll
      for (int kk = 0; kk < 16; ++kk) {
        bf16x8 Bf = __builtin_bit_cast(bf16x8, hq[kk]);
        int sw = (kk * 64 + lg * 16) ^ ((lr & 7) << 4);
        bf16x8 a0 = *(const bf16x8*)(wlds + lr * 1024 + sw);
        bf16x8 a1 = *(const bf16x8*)(wlds + (16 + lr) * 1024 + sw);
        acc0 = __builtin_amdgcn_mfma_f32_16x16x32_bf16(a0, Bf, acc0, 0, 0, 0);
        acc1 = __builtin_amdgcn_mfma_f32_16x16x32_bf16(a1, Bf, acc1, 0, 0, 0);
      }
    }

    const bool m = (t < mylen);
    float hn0, hn1;
    {  // mt = 0: unit = lg, regs = i,f,g,o
      float gi = acc0[0] + b2f(xc0[0]);
      float gf = acc0[1] + b2f(xc0[1]);
      float gg = acc0[2] + b2f(xc0[2]);
      float go = acc0[3] + b2f(xc0[3]);
      float ii = sigm_(gi), ff = sigm_(gf), gv = tanh_(gg), oo = sigm_(go);
      float cn = ff * cc0 + ii * gv;
      hn0 = oo * tanh_(cn);
      cc0 = m ? cn : cc0;
      h0 = m ? hn0 : h0;
    }
    {  // mt = 1: unit = 4 + lg
      float gi = acc1[0] + b2f(xc1[0]);
      float gf = acc1[1] + b2f(xc1[1]);
      float gg = acc1[2] + b2f(xc1[2]);
      float go = acc1[3] + b2f(xc1[3]);
      float ii = sigm_(gi), ff = sigm_(gf), gv = tanh_(gg), oo = sigm_(go);
      float cn = ff * cc1 + ii * gv;
      hn1 = oo * tanh_(cn);
      cc1 = m ? cn : cc1;
      h1 = m ? hn1 : h1;
    }

    // ---- publish: one packed dword (units lg, lg+4 of my batch) -> drain
    //      -> per-wave flag.  Critical path ends at the flag store.
    {
      unsigned pk = (unsigned)(unsigned short)f2bf(h0)
                  | ((unsigned)(unsigned short)f2bf(h1) << 16);
      unsigned* hw = hbuf + (size_t)(t & 1) * 16384 + batch * 256 + j * 4 + lg;
      asm volatile("global_store_dword %0, %1, off sc0 sc1"
                   :: "v"(hw), "v"(pk) : "memory");
      asm volatile("s_waitcnt vmcnt(0)" ::: "memory");
      if (lane == 0) {
        int tv = t + 1;
        asm volatile("global_store_dword %0, %1, off sc0 sc1"
                     :: "v"(fmine), "v"(tv) : "memory");
      }
      __builtin_amdgcn_sched_barrier(0);
    }

    // ---- slow ops AFTER the flag: out store + x(t+1) prefetch (retire
    //      during the next step's poll+bulk; next drain is a full step away)
    outb[(size_t)t * 512] = m ? hn0 : 0.0f;
    outb[(size_t)t * 512 + 4] = m ? hn1 : 0.0f;
    if (t + 1 < nt) {
      const short* xp = xbase + (size_t)(t + 1) * 2048;
      xc0 = *(const s16x4*)(xp);
      xc1 = *(const s16x4*)(xp + 16);
    }
  }

  // zero tail of the sequence output (t >= nt >= all xlen)
  for (int t = nt; t < 512; ++t) {
    outb[(size_t)t * 512] = 0.0f;
    outb[(size_t)t * 512 + 4] = 0.0f;
  }

  // final hidden state hT -> out[B*L*D + batch*512 + hid]
  float* oh = out + (size_t)64 * 512 * 512 + (size_t)batch * 512 + j * 8;
  oh[lg] = h0;
  oh[4 + lg] = h1;
}

// ---------------------------------------------------------------------------
extern "C" void kernel_launch(void* const* d_in, const int* in_sizes, int n_in,
                              void* d_out, int out_size, void* d_ws, size_t ws_size,
                              hipStream_t stream) {
  const int*   X      = (const int*)d_in[0];
  const int*   Xlen   = (const int*)d_in[1];
  const int*   aspect = (const int*)d_in[2];
  const int*   alen   = (const int*)d_in[3];
  const float* emb    = (const float*)d_in[4];
  const float* W_ih   = (const float*)d_in[5];
  const float* W_hh   = (const float*)d_in[6];
  const float* b_ih   = (const float*)d_in[7];
  const float* b_hh   = (const float*)d_in[8];
  float* out = (float*)d_out;

  char* ws = (char*)d_ws;
  // offsets (bytes)
  float*    asp_emb = (float*)(ws + 0);           //    131072
  float*    aspc    = (float*)(ws + 131072);      //    524288
  short*    W1p     = (short*)(ws + 655360);      //   2097152
  short*    Whp     = (short*)(ws + 2752512);     //   2097152
  unsigned* hbuf    = (unsigned*)(ws + 4849664);  //    131072 (2 gens x 16384 u32)
  int*      flags   = (int*)  (ws + 4980736);     //      4096 (256 used: [w][j])
  short*    word    = (short*)(ws + 4984832);     //  33554432
  short*    xproj   = (short*)(ws + 38539264);    // 134217728  (total ~165MB)

  float* out_hT  = out + (size_t)64 * 512 * 512;            // (1,B,D)
  float* out_asp = out_hT + (size_t)64 * 512;               // (B,D)

  hipLaunchKernelGGL(k_asp,    dim3(64),        dim3(128), 0, stream,
                     aspect, alen, emb, asp_emb, out_asp, flags);
  hipLaunchKernelGGL(k_pack,   dim3(2048),      dim3(128), 0, stream,
                     W_ih, W_hh, W1p, Whp);
  hipLaunchKernelGGL(k_aspc,   dim3(64),        dim3(256), 0, stream,
                     asp_emb, W_ih, b_ih, b_hh, aspc);
  hipLaunchKernelGGL(k_gather, dim3(16384),     dim3(256), 0, stream,
                     X, Xlen, emb, word);
  hipLaunchKernelGGL(k_gemm,   dim3(256, 16),   dim3(256), 0, stream,
                     word, W1p, aspc, Xlen, xproj);
  hipLaunchKernelGGL(k_rnn,    dim3(64),        dim3(256), 0, stream,
                     xproj, Whp, Xlen, hbuf, flags, out);
}

// Round 6
// 2279.090 us; speedup vs baseline: 2.2348x; 1.5181x over previous
//
#include <hip/hip_runtime.h>

// ATAE-LSTM fused pipeline for MI355X (gfx950).
// V=50000, D=512, B=64, L=512, A=4, 4D=2048.

using f32x4  = __attribute__((ext_vector_type(4))) float;
using s16x4  = __attribute__((ext_vector_type(4))) short;
using bf16x8 = __attribute__((ext_vector_type(8))) __bf16;

#define LOG2E 1.4426950408889634f

__device__ __forceinline__ float b2f(short s) {
  union { unsigned u; float f; } c;
  c.u = ((unsigned)(unsigned short)s) << 16;
  return c.f;
}
__device__ __forceinline__ short f2bf(float f) {
  union { float f; unsigned u; } c; c.f = f;
  unsigned r = (c.u + 0x7FFFu + ((c.u >> 16) & 1u)) >> 16;
  return (short)(unsigned short)r;
}
__device__ __forceinline__ float sigm_(float x) {
  float e = __builtin_amdgcn_exp2f(-x * LOG2E);
  return __builtin_amdgcn_rcpf(1.0f + e);
}
__device__ __forceinline__ float tanh_(float x) {
  float e = __builtin_amdgcn_exp2f(x * (2.0f * LOG2E));
  return 1.0f - 2.0f * __builtin_amdgcn_rcpf(1.0f + e);
}

// ---------------------------------------------------------------------------
// K1a: aspect embedding average; zeroes the 1024-dword flag region (fresh
// each launch -> graph-replay deterministic).
__global__ void k_asp(const int* __restrict__ aspect, const int* __restrict__ alen,
                      const float* __restrict__ emb, float* __restrict__ asp_emb,
                      float* __restrict__ out_asp, int* __restrict__ flags) {
  int b = blockIdx.x;          // 64
  int t = threadIdx.x;         // 128, 4 floats each
  if (b < 8) flags[b * 128 + t] = 0;   // 4KB of flags ([j][w] at j*16+w dwords)
  f32x4 s = {0.f, 0.f, 0.f, 0.f};
  #pragma unroll
  for (int a = 0; a < 4; ++a) {
    int idx = aspect[b * 4 + a];
    s += *(const f32x4*)(emb + (size_t)idx * 512 + t * 4);
  }
  float inv = 1.0f / (float)alen[b];
  s[0] *= inv; s[1] *= inv; s[2] *= inv; s[3] *= inv;
  *(f32x4*)(asp_emb + (size_t)b * 512 + t * 4) = s;
  *(f32x4*)(out_asp + (size_t)b * 512 + t * 4) = s;
}

// ---------------------------------------------------------------------------
// K1b: pack W_ih (word half) and W_hh rows into block-interleaved gate order,
// bf16.  Packed row P: j=P>>5 (block), u=(P>>2)&7 (unit), gate=P&3;
// source gate row gr = gate*512 + j*8 + u.
// Whp ONLY: K-columns permuted within each 8-group (position c <- unit
// (c&1)*4 + (c>>1)&3) so a producer thread's (h_lg, h_{lg+4}) pair is one
// dword and the consumer's B-fragment dword order matches (validated R2/R5).
__global__ void k_pack(const float* __restrict__ W_ih, const float* __restrict__ W_hh,
                       short* __restrict__ W1p, short* __restrict__ Whp) {
  int P = blockIdx.x;          // 2048
  int t = threadIdx.x;         // 128, 4 elems each
  int gr = (P & 3) * 512 + (P >> 5) * 8 + ((P >> 2) & 7);
  f32x4 w1 = *(const f32x4*)(W_ih + (size_t)gr * 1024 + t * 4);
  s16x4 o1, oh;
  #pragma unroll
  for (int i = 0; i < 4; ++i) {
    o1[i] = f2bf(w1[i]);
    int c = t * 4 + i;
    int ks = (c & ~7) | (((c & 1) << 2) | ((c >> 1) & 3));
    oh[i] = f2bf(W_hh[(size_t)gr * 512 + ks]);
  }
  *(s16x4*)(W1p + (size_t)P * 512 + t * 4) = o1;
  *(s16x4*)(Whp + (size_t)P * 512 + t * 4) = oh;
}

// ---------------------------------------------------------------------------
// K1c: asp_contrib[b][P] = asp_emb[b] . W_ih[gr][512:1024] + b_ih[gr] + b_hh[gr]
__global__ void k_aspc(const float* __restrict__ asp_emb, const float* __restrict__ W_ih,
                       const float* __restrict__ b_ih, const float* __restrict__ b_hh,
                       float* __restrict__ aspc) {
  int tid = threadIdx.x;                 // 256
  int P = blockIdx.x * 32 + (tid >> 3);  // 64 blocks
  int gr = (P & 3) * 512 + (P >> 5) * 8 + ((P >> 2) & 7);
  const float* wrow = W_ih + (size_t)gr * 1024 + 512;
  float bias = b_ih[gr] + b_hh[gr];
  int b0 = (tid & 7) * 8;
  float a[8];
  #pragma unroll
  for (int i = 0; i < 8; ++i) a[i] = 0.f;
  for (int k = 0; k < 512; k += 4) {
    f32x4 wv = *(const f32x4*)(wrow + k);
    #pragma unroll
    for (int bb = 0; bb < 8; ++bb) {
      f32x4 av = *(const f32x4*)(asp_emb + (size_t)(b0 + bb) * 512 + k);
      a[bb] += wv[0] * av[0] + wv[1] * av[1] + wv[2] * av[2] + wv[3] * av[3];
    }
  }
  #pragma unroll
  for (int bb = 0; bb < 8; ++bb) aspc[(size_t)(b0 + bb) * 2048 + P] = a[bb] + bias;
}

// ---------------------------------------------------------------------------
// K2: word embedding gather -> bf16, zero masked rows.
__global__ void k_gather(const int* __restrict__ X, const int* __restrict__ xlen,
                         const float* __restrict__ emb, short* __restrict__ word) {
  int g = blockIdx.x * 256 + threadIdx.x;  // 16384 blocks
  int row = g >> 7;                        // 128 threads per row
  int k4 = (g & 127) << 2;
  int b = row >> 9, l = row & 511;
  s16x4 o;
  if (l < xlen[b]) {
    int idx = X[row];
    f32x4 v = *(const f32x4*)(emb + (size_t)idx * 512 + k4);
    o[0] = f2bf(v[0]); o[1] = f2bf(v[1]); o[2] = f2bf(v[2]); o[3] = f2bf(v[3]);
  } else {
    o[0] = 0; o[1] = 0; o[2] = 0; o[3] = 0;
  }
  *(s16x4*)(word + (size_t)row * 512 + k4) = o;
}

// ---------------------------------------------------------------------------
// K3: GEMM  xproj[(b,l)][P] = word[(b,l),:] . W1p[P,:] + aspc[b][P]   (bf16 out)
__global__ __launch_bounds__(256)
void k_gemm(const short* __restrict__ A, const short* __restrict__ B,
            const float* __restrict__ aspc, const int* __restrict__ xlen,
            short* __restrict__ C) {
  __shared__ char smem[65536];  // A0 A1 B0 B1, 16KB each
  const int rt = blockIdx.x, ct = blockIdx.y;
  const int b = rt >> 2;
  if (xlen[b] <= ((rt & 3) << 7)) return;  // fully-masked row tile
  const int tid = threadIdx.x;
  const int w = tid >> 6, lane = tid & 63;
  const int lr = lane & 15, lg = lane >> 4;
  const int wr = (w & 1) * 64, wc = (w >> 1) * 64;
  const char* Ab = (const char*)(A + (size_t)rt * 128 * 512);
  const char* Bb = (const char*)(B + (size_t)ct * 128 * 512);

  f32x4 acc[4][4];
  #pragma unroll
  for (int mi = 0; mi < 4; ++mi)
    #pragma unroll
    for (int ni = 0; ni < 4; ++ni) acc[mi][ni] = {0.f, 0.f, 0.f, 0.f};

  auto stage = [&](int kt, int buf) {
    #pragma unroll
    for (int p = 0; p < 4; ++p) {
      int dbase = w * 1024 + p * 4096;   // wave-uniform LDS base
      int d = dbase + (lane << 4);
      int row = d >> 7;
      int kb = (d & 127) ^ (((d >> 9) & 1) << 5);  // pre-swizzled source
      __builtin_amdgcn_global_load_lds(
          (const __attribute__((address_space(1))) unsigned*)(Ab + (size_t)row * 1024 + kt * 128 + kb),
          (__attribute__((address_space(3))) unsigned*)(smem + buf * 16384 + dbase), 16, 0, 0);
      __builtin_amdgcn_global_load_lds(
          (const __attribute__((address_space(1))) unsigned*)(Bb + (size_t)row * 1024 + kt * 128 + kb),
          (__attribute__((address_space(3))) unsigned*)(smem + 32768 + buf * 16384 + dbase), 16, 0, 0);
    }
  };

  stage(0, 0);
  __syncthreads();
  #pragma unroll 1
  for (int kt = 0; kt < 8; ++kt) {
    int cur = kt & 1;
    if (kt < 7) stage(kt + 1, cur ^ 1);
    const char* sAc = smem + cur * 16384;
    const char* sBc = smem + 32768 + cur * 16384;
    #pragma unroll
    for (int kk = 0; kk < 2; ++kk) {
      bf16x8 af[4], bfr[4];
      #pragma unroll
      for (int mi = 0; mi < 4; ++mi) {
        int lin = (wr + mi * 16 + lr) * 128 + kk * 64 + lg * 16;
        af[mi] = *(const bf16x8*)(sAc + (lin ^ (((lin >> 9) & 1) << 5)));
      }
      #pragma unroll
      for (int ni = 0; ni < 4; ++ni) {
        int lin = (wc + ni * 16 + lr) * 128 + kk * 64 + lg * 16;
        bfr[ni] = *(const bf16x8*)(sBc + (lin ^ (((lin >> 9) & 1) << 5)));
      }
      #pragma unroll
      for (int mi = 0; mi < 4; ++mi)
        #pragma unroll
        for (int ni = 0; ni < 4; ++ni)
          acc[mi][ni] = __builtin_amdgcn_mfma_f32_16x16x32_bf16(af[mi], bfr[ni], acc[mi][ni], 0, 0, 0);
    }
    __syncthreads();
  }

  const int colb = ct * 128 + wc;
  float cb[4];
  #pragma unroll
  for (int ni = 0; ni < 4; ++ni) cb[ni] = aspc[(size_t)b * 2048 + colb + ni * 16 + lr];
  #pragma unroll
  for (int mi = 0; mi < 4; ++mi) {
    const int row0 = rt * 128 + wr + mi * 16 + lg * 4;
    #pragma unroll
    for (int r = 0; r < 4; ++r) {
      short* crow = C + (size_t)(row0 + r) * 2048 + colb + lr;
      #pragma unroll
      for (int ni = 0; ni < 4; ++ni)
        crow[ni * 16] = f2bf(acc[mi][ni][r] + cb[ni]);
    }
  }
}

// ---------------------------------------------------------------------------
// K4: persistent LSTM recurrence, contention-isolated flag-gated exchange.
//  - hbuf j-major: hbuf[parity][j][batch] = 16B written ONLY by block j
//    (4 lg-dwords), read by consumers as one dwordx4 (Bf[kk] @ j=kk*4+lg).
//  - flags[j][w] at byte j*64+w*4: each flag LINE written only by block j.
//  - slow ops (out-store of t-1, x(t) load) issued between poll success and
//    bulk read -> overlapped by the bulk vmcnt(0); publish drain sees only
//    the exclusive-line h-store; poll drain sees only flag loads.
__global__ __launch_bounds__(256, 1)
void k_rnn(const short* __restrict__ xproj, const short* __restrict__ Whp,
           const int* __restrict__ xlen, unsigned* hbuf, int* flags,
           float* __restrict__ out) {
  __shared__ char wlds[32768];
  const int j = blockIdx.x;       // 64
  const int tid = threadIdx.x;
  const int w = tid >> 6;
  const int lane = tid & 63;
  const int lr = lane & 15, lg = lane >> 4;
  const int batch = w * 16 + lr;
  const int mylen = xlen[batch];

  // block-uniform max sequence length (identical in every block)
  int nt = xlen[lane];
  #pragma unroll
  for (int d = 32; d; d >>= 1) nt = max(nt, __shfl_xor(nt, d));

  // stage this block's W_hh slice (32 rows x 512 cols bf16 = 32KB) into LDS,
  // XOR-swizzled (row&7)<<4 against the stride-1024 bank conflict.
  {
    const char* src = (const char*)(Whp + (size_t)j * 32 * 512);
    int base = tid * 128;
    int row = base >> 10;
    int c0 = base & 1023;
    #pragma unroll
    for (int i = 0; i < 8; ++i) {
      int c = c0 + i * 16;
      *(f32x4*)(wlds + row * 1024 + (c ^ ((row & 7) << 4))) =
          *(const f32x4*)(src + (size_t)row * 1024 + c);
    }
  }
  __syncthreads();

  float cc0 = 0.f, cc1 = 0.f, h0 = 0.f, h1 = 0.f;
  float po0 = 0.f, po1 = 0.f;           // deferred out values (step t-1)
  const short* xbase = xproj + (size_t)batch * 512 * 2048 + j * 32 + lg * 4;
  float* outb = out + (size_t)batch * 512 * 512 + (size_t)j * 8 + lg;
  const int* fpoll = flags + lane * 16 + w;   // lane j' polls flag[j'][w]
  int* fmine = flags + j * 16 + w;            // my flag (lane0 stores)

  s16x4 xc0 = *(const s16x4*)(xbase);         // x(t=0), mt=0 (i,f,g,o)
  s16x4 xc1 = *(const s16x4*)(xbase + 16);    // mt=1

  #pragma unroll 1
  for (int t = 0; t < nt; ++t) {
    f32x4 acc0 = {0.f, 0.f, 0.f, 0.f}, acc1 = {0.f, 0.f, 0.f, 0.f};
    if (t > 0) {
      // ---- poll my 64 producers' flags (one exclusive line each)
      {
        int fv;
        asm volatile("global_load_dword %0, %1, off sc0 sc1"
                     : "=&v"(fv) : "v"(fpoll) : "memory");
        asm volatile("s_waitcnt vmcnt(0)" ::: "memory");
        while (!__all((unsigned)fv >= (unsigned)t)) {
          __builtin_amdgcn_s_sleep(1);
          asm volatile("global_load_dword %0, %1, off sc0 sc1"
                       : "=&v"(fv) : "v"(fpoll) : "memory");
          asm volatile("s_waitcnt vmcnt(0)" ::: "memory");
        }
      }
      __builtin_amdgcn_sched_barrier(0);
      // ---- slow ops issued here: overlapped by the bulk read's drain
      outb[(size_t)(t - 1) * 512] = po0;       // out(t-1), scattered HBM
      outb[(size_t)(t - 1) * 512 + 4] = po1;
      {                                         // x(t) load (L2/HBM)
        const short* xp = xbase + (size_t)t * 2048;
        xc0 = *(const s16x4*)(xp);
        xc1 = *(const s16x4*)(xp + 16);
      }
      // ---- bulk h(t-1) read: Bf[kk] = dwordx4 @ hbuf[j'=kk*4+lg][batch]
      const char* hbL = (const char*)hbuf + (size_t)((t - 1) & 1) * 65536
                        + batch * 16;
      int4 hq[16];
      #pragma unroll
      for (int kk = 0; kk < 16; ++kk)
        asm volatile("global_load_dwordx4 %0, %1, off sc0 sc1"
                     : "=&v"(hq[kk]) : "v"(hbL + (kk * 4 + lg) * 1024) : "memory");
      asm volatile("s_waitcnt vmcnt(0)" ::: "memory");
      __builtin_amdgcn_sched_barrier(0);
      // ---- MFMA: gates += W_hh . h(t-1)
      #pragma unroll
      for (int kk = 0; kk < 16; ++kk) {
        bf16x8 Bf = __builtin_bit_cast(bf16x8, hq[kk]);
        int sw = (kk * 64 + lg * 16) ^ ((lr & 7) << 4);
        bf16x8 a0 = *(const bf16x8*)(wlds + lr * 1024 + sw);
        bf16x8 a1 = *(const bf16x8*)(wlds + (16 + lr) * 1024 + sw);
        acc0 = __builtin_amdgcn_mfma_f32_16x16x32_bf16(a0, Bf, acc0, 0, 0, 0);
        acc1 = __builtin_amdgcn_mfma_f32_16x16x32_bf16(a1, Bf, acc1, 0, 0, 0);
      }
    }

    const bool m = (t < mylen);
    float hn0, hn1;
    {  // mt = 0: unit = lg, regs = i,f,g,o
      float gi = acc0[0] + b2f(xc0[0]);
      float gf = acc0[1] + b2f(xc0[1]);
      float gg = acc0[2] + b2f(xc0[2]);
      float go = acc0[3] + b2f(xc0[3]);
      float ii = sigm_(gi), ff = sigm_(gf), gv = tanh_(gg), oo = sigm_(go);
      float cn = ff * cc0 + ii * gv;
      hn0 = oo * tanh_(cn);
      cc0 = m ? cn : cc0;
      h0 = m ? hn0 : h0;
    }
    {  // mt = 1: unit = 4 + lg
      float gi = acc1[0] + b2f(xc1[0]);
      float gf = acc1[1] + b2f(xc1[1]);
      float gg = acc1[2] + b2f(xc1[2]);
      float go = acc1[3] + b2f(xc1[3]);
      float ii = sigm_(gi), ff = sigm_(gf), gv = tanh_(gg), oo = sigm_(go);
      float cn = ff * cc1 + ii * gv;
      hn1 = oo * tanh_(cn);
      cc1 = m ? cn : cc1;
      h1 = m ? hn1 : h1;
    }

    // ---- publish: packed dword to MY exclusive region -> drain -> flag
    {
      unsigned pk = (unsigned)(unsigned short)f2bf(h0)
                  | ((unsigned)(unsigned short)f2bf(h1) << 16);
      unsigned* hw = hbuf + (size_t)(t & 1) * 16384 + j * 256 + batch * 4 + lg;
      asm volatile("global_store_dword %0, %1, off sc0 sc1"
                   :: "v"(hw), "v"(pk) : "memory");
      asm volatile("s_waitcnt vmcnt(0)" ::: "memory");  // h-store only
      if (lane == 0) {
        int tv = t + 1;
        asm volatile("global_store_dword %0, %1, off sc0 sc1"
                     :: "v"(fmine), "v"(tv) : "memory");  // fire-and-forget
      }
      __builtin_amdgcn_sched_barrier(0);
    }

    // stage out(t) for deferred store
    po0 = m ? hn0 : 0.0f;
    po1 = m ? hn1 : 0.0f;
  }

  // final deferred out-store (step nt-1)
  outb[(size_t)(nt - 1) * 512] = po0;
  outb[(size_t)(nt - 1) * 512 + 4] = po1;

  // zero tail of the sequence output (t >= nt >= all xlen)
  for (int t = nt; t < 512; ++t) {
    outb[(size_t)t * 512] = 0.0f;
    outb[(size_t)t * 512 + 4] = 0.0f;
  }

  // final hidden state hT -> out[B*L*D + batch*512 + hid]
  float* oh = out + (size_t)64 * 512 * 512 + (size_t)batch * 512 + j * 8;
  oh[lg] = h0;
  oh[4 + lg] = h1;
}

// ---------------------------------------------------------------------------
extern "C" void kernel_launch(void* const* d_in, const int* in_sizes, int n_in,
                              void* d_out, int out_size, void* d_ws, size_t ws_size,
                              hipStream_t stream) {
  const int*   X      = (const int*)d_in[0];
  const int*   Xlen   = (const int*)d_in[1];
  const int*   aspect = (const int*)d_in[2];
  const int*   alen   = (const int*)d_in[3];
  const float* emb    = (const float*)d_in[4];
  const float* W_ih   = (const float*)d_in[5];
  const float* W_hh   = (const float*)d_in[6];
  const float* b_ih   = (const float*)d_in[7];
  const float* b_hh   = (const float*)d_in[8];
  float* out = (float*)d_out;

  char* ws = (char*)d_ws;
  // offsets (bytes)
  float*    asp_emb = (float*)(ws + 0);           //    131072
  float*    aspc    = (float*)(ws + 131072);      //    524288
  short*    W1p     = (short*)(ws + 655360);      //   2097152
  short*    Whp     = (short*)(ws + 2752512);     //   2097152
  unsigned* hbuf    = (unsigned*)(ws + 4849664);  //    131072 (2 par x 64KB, j-major)
  int*      flags   = (int*)  (ws + 4980736);     //      4096 ([j][w] @ j*64+w*4 B)
  short*    word    = (short*)(ws + 4984832);     //  33554432
  short*    xproj   = (short*)(ws + 38539264);    // 134217728  (total ~165MB)

  float* out_hT  = out + (size_t)64 * 512 * 512;            // (1,B,D)
  float* out_asp = out_hT + (size_t)64 * 512;               // (B,D)

  hipLaunchKernelGGL(k_asp,    dim3(64),        dim3(128), 0, stream,
                     aspect, alen, emb, asp_emb, out_asp, flags);
  hipLaunchKernelGGL(k_pack,   dim3(2048),      dim3(128), 0, stream,
                     W_ih, W_hh, W1p, Whp);
  hipLaunchKernelGGL(k_aspc,   dim3(64),        dim3(256), 0, stream,
                     asp_emb, W_ih, b_ih, b_hh, aspc);
  hipLaunchKernelGGL(k_gather, dim3(16384),     dim3(256), 0, stream,
                     X, Xlen, emb, word);
  hipLaunchKernelGGL(k_gemm,   dim3(256, 16),   dim3(256), 0, stream,
                     word, W1p, aspc, Xlen, xproj);
  hipLaunchKernelGGL(k_rnn,    dim3(64),        dim3(256), 0, stream,
                     xproj, Whp, Xlen, hbuf, flags, out);
}

// Round 8
// 2071.572 us; speedup vs baseline: 2.4586x; 1.1002x over previous
//
#include <hip/hip_runtime.h>

// ATAE-LSTM fused pipeline for MI355X (gfx950).
// V=50000, D=512, B=64, L=512, A=4, 4D=2048.
// k_rnn v8: tagged h exchange (R3-validated) on block-exclusive lines
// (R6-validated layout). No flags, no drains on the critical path.

using f32x4  = __attribute__((ext_vector_type(4))) float;
using s16x4  = __attribute__((ext_vector_type(4))) short;
using bf16x8 = __attribute__((ext_vector_type(8))) __bf16;

#define LOG2E 1.4426950408889634f

__device__ __forceinline__ float b2f(short s) {
  union { unsigned u; float f; } c;
  c.u = ((unsigned)(unsigned short)s) << 16;
  return c.f;
}
__device__ __forceinline__ short f2bf(float f) {
  union { float f; unsigned u; } c; c.f = f;
  unsigned r = (c.u + 0x7FFFu + ((c.u >> 16) & 1u)) >> 16;
  return (short)(unsigned short)r;
}
__device__ __forceinline__ float sigm_(float x) {
  float e = __builtin_amdgcn_exp2f(-x * LOG2E);
  return __builtin_amdgcn_rcpf(1.0f + e);
}
__device__ __forceinline__ float tanh_(float x) {
  float e = __builtin_amdgcn_exp2f(x * (2.0f * LOG2E));
  return 1.0f - 2.0f * __builtin_amdgcn_rcpf(1.0f + e);
}

// ---------------------------------------------------------------------------
// K1a: aspect embedding average; zeroes hbuf (256KB of tags must start 0
// every launch -> graph-replay deterministic).
__global__ void k_asp(const int* __restrict__ aspect, const int* __restrict__ alen,
                      const float* __restrict__ emb, float* __restrict__ asp_emb,
                      float* __restrict__ out_asp, unsigned* __restrict__ hbuf) {
  int b = blockIdx.x;          // 64
  int t = threadIdx.x;         // 128, 4 floats each
  {
    unsigned* hz = hbuf + (size_t)(b * 128 + t) * 8;  // 8192 thr x 8 u32 = 256KB
    #pragma unroll
    for (int i = 0; i < 8; ++i) hz[i] = 0u;
  }
  f32x4 s = {0.f, 0.f, 0.f, 0.f};
  #pragma unroll
  for (int a = 0; a < 4; ++a) {
    int idx = aspect[b * 4 + a];
    s += *(const f32x4*)(emb + (size_t)idx * 512 + t * 4);
  }
  float inv = 1.0f / (float)alen[b];
  s[0] *= inv; s[1] *= inv; s[2] *= inv; s[3] *= inv;
  *(f32x4*)(asp_emb + (size_t)b * 512 + t * 4) = s;
  *(f32x4*)(out_asp + (size_t)b * 512 + t * 4) = s;
}

// ---------------------------------------------------------------------------
// K1b: pack W_ih (word half) and W_hh rows into block-interleaved gate order,
// bf16.  Packed row P: j=P>>5 (block), u=(P>>2)&7 (unit), gate=P&3;
// source gate row gr = gate*512 + j*8 + u.
// Whp ONLY: K-columns permuted within each 8-group (slot c <- unit
// (c&1)*4 + (c>>1)&3) so producer thread lg's (h_lg, h_{lg+4}) pair lands in
// consecutive slots 2lg,2lg+1 (validated R2/R5/R6).
__global__ void k_pack(const float* __restrict__ W_ih, const float* __restrict__ W_hh,
                       short* __restrict__ W1p, short* __restrict__ Whp) {
  int P = blockIdx.x;          // 2048
  int t = threadIdx.x;         // 128, 4 elems each
  int gr = (P & 3) * 512 + (P >> 5) * 8 + ((P >> 2) & 7);
  f32x4 w1 = *(const f32x4*)(W_ih + (size_t)gr * 1024 + t * 4);
  s16x4 o1, oh;
  #pragma unroll
  for (int i = 0; i < 4; ++i) {
    o1[i] = f2bf(w1[i]);
    int c = t * 4 + i;
    int ks = (c & ~7) | (((c & 1) << 2) | ((c >> 1) & 3));
    oh[i] = f2bf(W_hh[(size_t)gr * 512 + ks]);
  }
  *(s16x4*)(W1p + (size_t)P * 512 + t * 4) = o1;
  *(s16x4*)(Whp + (size_t)P * 512 + t * 4) = oh;
}

// ---------------------------------------------------------------------------
// K1c: asp_contrib[b][P] = asp_emb[b] . W_ih[gr][512:1024] + b_ih[gr] + b_hh[gr]
__global__ void k_aspc(const float* __restrict__ asp_emb, const float* __restrict__ W_ih,
                       const float* __restrict__ b_ih, const float* __restrict__ b_hh,
                       float* __restrict__ aspc) {
  int tid = threadIdx.x;                 // 256
  int P = blockIdx.x * 32 + (tid >> 3);  // 64 blocks
  int gr = (P & 3) * 512 + (P >> 5) * 8 + ((P >> 2) & 7);
  const float* wrow = W_ih + (size_t)gr * 1024 + 512;
  float bias = b_ih[gr] + b_hh[gr];
  int b0 = (tid & 7) * 8;
  float a[8];
  #pragma unroll
  for (int i = 0; i < 8; ++i) a[i] = 0.f;
  for (int k = 0; k < 512; k += 4) {
    f32x4 wv = *(const f32x4*)(wrow + k);
    #pragma unroll
    for (int bb = 0; bb < 8; ++bb) {
      f32x4 av = *(const f32x4*)(asp_emb + (size_t)(b0 + bb) * 512 + k);
      a[bb] += wv[0] * av[0] + wv[1] * av[1] + wv[2] * av[2] + wv[3] * av[3];
    }
  }
  #pragma unroll
  for (int bb = 0; bb < 8; ++bb) aspc[(size_t)(b0 + bb) * 2048 + P] = a[bb] + bias;
}

// ---------------------------------------------------------------------------
// K2: word embedding gather -> bf16, zero masked rows.
__global__ void k_gather(const int* __restrict__ X, const int* __restrict__ xlen,
                         const float* __restrict__ emb, short* __restrict__ word) {
  int g = blockIdx.x * 256 + threadIdx.x;  // 16384 blocks
  int row = g >> 7;                        // 128 threads per row
  int k4 = (g & 127) << 2;
  int b = row >> 9, l = row & 511;
  s16x4 o;
  if (l < xlen[b]) {
    int idx = X[row];
    f32x4 v = *(const f32x4*)(emb + (size_t)idx * 512 + k4);
    o[0] = f2bf(v[0]); o[1] = f2bf(v[1]); o[2] = f2bf(v[2]); o[3] = f2bf(v[3]);
  } else {
    o[0] = 0; o[1] = 0; o[2] = 0; o[3] = 0;
  }
  *(s16x4*)(word + (size_t)row * 512 + k4) = o;
}

// ---------------------------------------------------------------------------
// K3: GEMM  xproj[(b,l)][P] = word[(b,l),:] . W1p[P,:] + aspc[b][P]   (bf16 out)
__global__ __launch_bounds__(256)
void k_gemm(const short* __restrict__ A, const short* __restrict__ B,
            const float* __restrict__ aspc, const int* __restrict__ xlen,
            short* __restrict__ C) {
  __shared__ char smem[65536];  // A0 A1 B0 B1, 16KB each
  const int rt = blockIdx.x, ct = blockIdx.y;
  const int b = rt >> 2;
  if (xlen[b] <= ((rt & 3) << 7)) return;  // fully-masked row tile
  const int tid = threadIdx.x;
  const int w = tid >> 6, lane = tid & 63;
  const int lr = lane & 15, lg = lane >> 4;
  const int wr = (w & 1) * 64, wc = (w >> 1) * 64;
  const char* Ab = (const char*)(A + (size_t)rt * 128 * 512);
  const char* Bb = (const char*)(B + (size_t)ct * 128 * 512);

  f32x4 acc[4][4];
  #pragma unroll
  for (int mi = 0; mi < 4; ++mi)
    #pragma unroll
    for (int ni = 0; ni < 4; ++ni) acc[mi][ni] = {0.f, 0.f, 0.f, 0.f};

  auto stage = [&](int kt, int buf) {
    #pragma unroll
    for (int p = 0; p < 4; ++p) {
      int dbase = w * 1024 + p * 4096;   // wave-uniform LDS base
      int d = dbase + (lane << 4);
      int row = d >> 7;
      int kb = (d & 127) ^ (((d >> 9) & 1) << 5);  // pre-swizzled source
      __builtin_amdgcn_global_load_lds(
          (const __attribute__((address_space(1))) unsigned*)(Ab + (size_t)row * 1024 + kt * 128 + kb),
          (__attribute__((address_space(3))) unsigned*)(smem + buf * 16384 + dbase), 16, 0, 0);
      __builtin_amdgcn_global_load_lds(
          (const __attribute__((address_space(1))) unsigned*)(Bb + (size_t)row * 1024 + kt * 128 + kb),
          (__attribute__((address_space(3))) unsigned*)(smem + 32768 + buf * 16384 + dbase), 16, 0, 0);
    }
  };

  stage(0, 0);
  __syncthreads();
  #pragma unroll 1
  for (int kt = 0; kt < 8; ++kt) {
    int cur = kt & 1;
    if (kt < 7) stage(kt + 1, cur ^ 1);
    const char* sAc = smem + cur * 16384;
    const char* sBc = smem + 32768 + cur * 16384;
    #pragma unroll
    for (int kk = 0; kk < 2; ++kk) {
      bf16x8 af[4], bfr[4];
      #pragma unroll
      for (int mi = 0; mi < 4; ++mi) {
        int lin = (wr + mi * 16 + lr) * 128 + kk * 64 + lg * 16;
        af[mi] = *(const bf16x8*)(sAc + (lin ^ (((lin >> 9) & 1) << 5)));
      }
      #pragma unroll
      for (int ni = 0; ni < 4; ++ni) {
        int lin = (wc + ni * 16 + lr) * 128 + kk * 64 + lg * 16;
        bfr[ni] = *(const bf16x8*)(sBc + (lin ^ (((lin >> 9) & 1) << 5)));
      }
      #pragma unroll
      for (int mi = 0; mi < 4; ++mi)
        #pragma unroll
        for (int ni = 0; ni < 4; ++ni)
          acc[mi][ni] = __builtin_amdgcn_mfma_f32_16x16x32_bf16(af[mi], bfr[ni], acc[mi][ni], 0, 0, 0);
    }
    __syncthreads();
  }

  const int colb = ct * 128 + wc;
  float cb[4];
  #pragma unroll
  for (int ni = 0; ni < 4; ++ni) cb[ni] = aspc[(size_t)b * 2048 + colb + ni * 16 + lr];
  #pragma unroll
  for (int mi = 0; mi < 4; ++mi) {
    const int row0 = rt * 128 + wr + mi * 16 + lg * 4;
    #pragma unroll
    for (int r = 0; r < 4; ++r) {
      short* crow = C + (size_t)(row0 + r) * 2048 + colb + lr;
      #pragma unroll
      for (int ni = 0; ni < 4; ++ni)
        crow[ni * 16] = f2bf(acc[mi][ni][r] + cb[ni]);
    }
  }
}

// ---------------------------------------------------------------------------
// K4: persistent LSTM recurrence, tagged h exchange on exclusive lines.
// hbuf[par][j][batch] = 32B (8 dwords, slot s = K-permuted unit s of block j),
// dword = (bf16(h) << 16) | (t+1).  Producer: one dwordx2 store (slots
// 2lg,2lg+1), fire-and-forget.  Consumer wave w: reads 16 groups x 32B from
// exclusive lines, validates all 8 tags per group, retries only stale groups.
// Waves are fully decoupled (per-wave nt over its own 16 batches).
__global__ __launch_bounds__(256, 1)
void k_rnn(const short* __restrict__ xproj, const short* __restrict__ Whp,
           const int* __restrict__ xlen, unsigned* hbuf, float* __restrict__ out) {
  __shared__ char wlds[32768];
  const int j = blockIdx.x;       // 64
  const int tid = threadIdx.x;
  const int w = tid >> 6;
  const int lane = tid & 63;
  const int lr = lane & 15, lg = lane >> 4;
  const int batch = w * 16 + lr;
  const int mylen = xlen[batch];

  // per-WAVE max sequence length (reduce over lr only; waves decoupled)
  int nt = xlen[batch];
  #pragma unroll
  for (int d = 8; d; d >>= 1) nt = max(nt, __shfl_xor(nt, d));

  // stage this block's W_hh slice (32 rows x 512 cols bf16 = 32KB) into LDS,
  // XOR-swizzled (row&7)<<4 against the stride-1024 bank conflict.
  {
    const char* src = (const char*)(Whp + (size_t)j * 32 * 512);
    int base = tid * 128;
    int row = base >> 10;
    int c0 = base & 1023;
    #pragma unroll
    for (int i = 0; i < 8; ++i) {
      int c = c0 + i * 16;
      *(f32x4*)(wlds + row * 1024 + (c ^ ((row & 7) << 4))) =
          *(const f32x4*)(src + (size_t)row * 1024 + c);
    }
  }
  __syncthreads();

  float cc0 = 0.f, cc1 = 0.f, h0 = 0.f, h1 = 0.f;
  const short* xbase = xproj + (size_t)batch * 512 * 2048 + j * 32 + lg * 4;
  float* outb = out + (size_t)batch * 512 * 512 + (size_t)j * 8 + lg;
  char* hbB = (char*)hbuf;

  // depth-2 x prefetch
  s16x4 xc0 = *(const s16x4*)(xbase);
  s16x4 xc1 = *(const s16x4*)(xbase + 16);
  int i1 = (1 < nt) ? 1 : 0;
  s16x4 xn0 = *(const s16x4*)(xbase + (size_t)i1 * 2048);
  s16x4 xn1 = *(const s16x4*)(xbase + (size_t)i1 * 2048 + 16);

  #pragma unroll 1
  for (int t = 0; t < nt; ++t) {
    f32x4 acc0 = {0.f, 0.f, 0.f, 0.f}, acc1 = {0.f, 0.f, 0.f, 0.f};
    if (t > 0) {
      const char* hb = hbB + (size_t)((t - 1) & 1) * 131072 + batch * 32;
      const unsigned tneed = (unsigned)t;   // tag written at step t-1 is t
      int4 qa[16], qb[16];
      unsigned pend = 0xffffu;              // wave-uniform pending mask
      while (pend) {
        #pragma unroll
        for (int kk = 0; kk < 16; ++kk)
          if (pend & (1u << kk)) {
            const char* p = hb + (size_t)(kk * 4 + lg) * 2048;
            asm volatile("global_load_dwordx4 %0, %1, off sc0 sc1"
                         : "=&v"(qa[kk]) : "v"(p) : "memory");
            asm volatile("global_load_dwordx4 %0, %1, off sc0 sc1"
                         : "=&v"(qb[kk]) : "v"(p + 16) : "memory");
          }
        asm volatile("s_waitcnt vmcnt(0)" ::: "memory");
        __builtin_amdgcn_sched_barrier(0);
        #pragma unroll
        for (int kk = 0; kk < 16; ++kk)
          if (pend & (1u << kk)) {
            int4 q0 = qa[kk], q1 = qb[kk];
            unsigned m0 = min((unsigned)q0.x & 0xffffu, (unsigned)q0.y & 0xffffu);
            unsigned m1 = min((unsigned)q0.z & 0xffffu, (unsigned)q0.w & 0xffffu);
            unsigned m2 = min((unsigned)q1.x & 0xffffu, (unsigned)q1.y & 0xffffu);
            unsigned m3 = min((unsigned)q1.z & 0xffffu, (unsigned)q1.w & 0xffffu);
            unsigned mn = min(min(m0, m1), min(m2, m3));
            if (__all(mn >= tneed)) pend &= ~(1u << kk);
          }
      }
      __builtin_amdgcn_sched_barrier(0);
      // MFMA: gates += W_hh . h(t-1)
      #pragma unroll
      for (int kk = 0; kk < 16; ++kk) {
        int4 q0 = qa[kk], q1 = qb[kk];
        union { unsigned u[4]; bf16x8 v; } pk;
        pk.u[0] = ((unsigned)q0.x >> 16) | ((unsigned)q0.y & 0xffff0000u);
        pk.u[1] = ((unsigned)q0.z >> 16) | ((unsigned)q0.w & 0xffff0000u);
        pk.u[2] = ((unsigned)q1.x >> 16) | ((unsigned)q1.y & 0xffff0000u);
        pk.u[3] = ((unsigned)q1.z >> 16) | ((unsigned)q1.w & 0xffff0000u);
        int sw = (kk * 64 + lg * 16) ^ ((lr & 7) << 4);
        bf16x8 a0 = *(const bf16x8*)(wlds + lr * 1024 + sw);
        bf16x8 a1 = *(const bf16x8*)(wlds + (16 + lr) * 1024 + sw);
        acc0 = __builtin_amdgcn_mfma_f32_16x16x32_bf16(a0, pk.v, acc0, 0, 0, 0);
        acc1 = __builtin_amdgcn_mfma_f32_16x16x32_bf16(a1, pk.v, acc1, 0, 0, 0);
      }
    }

    const bool m = (t < mylen);
    float hn0, hn1;
    {  // mt = 0: unit = lg, regs = i,f,g,o
      float gi = acc0[0] + b2f(xc0[0]);
      float gf = acc0[1] + b2f(xc0[1]);
      float gg = acc0[2] + b2f(xc0[2]);
      float go = acc0[3] + b2f(xc0[3]);
      float ii = sigm_(gi), ff = sigm_(gf), gv = tanh_(gg), oo = sigm_(go);
      float cn = ff * cc0 + ii * gv;
      hn0 = oo * tanh_(cn);
      cc0 = m ? cn : cc0;
      h0 = m ? hn0 : h0;
    }
    {  // mt = 1: unit = 4 + lg
      float gi = acc1[0] + b2f(xc1[0]);
      float gf = acc1[1] + b2f(xc1[1]);
      float gg = acc1[2] + b2f(xc1[2]);
      float go = acc1[3] + b2f(xc1[3]);
      float ii = sigm_(gi), ff = sigm_(gf), gv = tanh_(gg), oo = sigm_(go);
      float cn = ff * cc1 + ii * gv;
      hn1 = oo * tanh_(cn);
      cc1 = m ? cn : cc1;
      h1 = m ? hn1 : h1;
    }

    // publish: tagged dword pair (slots 2lg,2lg+1) -> fire-and-forget
    {
      unsigned tag = (unsigned)(t + 1) & 0xffffu;
      unsigned d0 = ((unsigned)(unsigned short)f2bf(h0) << 16) | tag;
      unsigned d1 = ((unsigned)(unsigned short)f2bf(h1) << 16) | tag;
      unsigned long long pr = (unsigned long long)d0 | ((unsigned long long)d1 << 32);
      char* hw = hbB + (size_t)(t & 1) * 131072 + j * 2048 + batch * 32 + lg * 8;
      asm volatile("global_store_dwordx2 %0, %1, off sc0 sc1"
                   :: "v"(hw), "v"(pr) : "memory");
    }

    // slow ops after publish: retire during next step's first bulk pass
    outb[(size_t)t * 512] = m ? hn0 : 0.0f;
    outb[(size_t)t * 512 + 4] = m ? hn1 : 0.0f;
    int tn = (t + 2 < nt) ? t + 2 : nt - 1;
    const short* xp = xbase + (size_t)tn * 2048;
    xc0 = xn0; xc1 = xn1;
    xn0 = *(const s16x4*)(xp);
    xn1 = *(const s16x4*)(xp + 16);
  }

  // zero tail of the sequence output (t >= nt >= this wave's xlen)
  for (int t = nt; t < 512; ++t) {
    outb[(size_t)t * 512] = 0.0f;
    outb[(size_t)t * 512 + 4] = 0.0f;
  }

  // final hidden state hT -> out[B*L*D + batch*512 + hid]
  float* oh = out + (size_t)64 * 512 * 512 + (size_t)batch * 512 + j * 8;
  oh[lg] = h0;
  oh[4 + lg] = h1;
}

// ---------------------------------------------------------------------------
extern "C" void kernel_launch(void* const* d_in, const int* in_sizes, int n_in,
                              void* d_out, int out_size, void* d_ws, size_t ws_size,
                              hipStream_t stream) {
  const int*   X      = (const int*)d_in[0];
  const int*   Xlen   = (const int*)d_in[1];
  const int*   aspect = (const int*)d_in[2];
  const int*   alen   = (const int*)d_in[3];
  const float* emb    = (const float*)d_in[4];
  const float* W_ih   = (const float*)d_in[5];
  const float* W_hh   = (const float*)d_in[6];
  const float* b_ih   = (const float*)d_in[7];
  const float* b_hh   = (const float*)d_in[8];
  float* out = (float*)d_out;

  char* ws = (char*)d_ws;
  // offsets (bytes)
  float*    asp_emb = (float*)(ws + 0);           //    131072
  float*    aspc    = (float*)(ws + 131072);      //    524288
  short*    W1p     = (short*)(ws + 655360);      //   2097152
  short*    Whp     = (short*)(ws + 2752512);     //   2097152
  unsigned* hbuf    = (unsigned*)(ws + 4849664);  //    262144 (2 par x 64 j x 64 b x 32B)
  short*    word    = (short*)(ws + 5111808);     //  33554432
  short*    xproj   = (short*)(ws + 38666240);    // 134217728

  float* out_hT  = out + (size_t)64 * 512 * 512;            // (1,B,D)
  float* out_asp = out_hT + (size_t)64 * 512;               // (B,D)

  hipLaunchKernelGGL(k_asp,    dim3(64),        dim3(128), 0, stream,
                     aspect, alen, emb, asp_emb, out_asp, hbuf);
  hipLaunchKernelGGL(k_pack,   dim3(2048),      dim3(128), 0, stream,
                     W_ih, W_hh, W1p, Whp);
  hipLaunchKernelGGL(k_aspc,   dim3(64),        dim3(256), 0, stream,
                     asp_emb, W_ih, b_ih, b_hh, aspc);
  hipLaunchKernelGGL(k_gather, dim3(16384),     dim3(256), 0, stream,
                     X, Xlen, emb, word);
  hipLaunchKernelGGL(k_gemm,   dim3(256, 16),   dim3(256), 0, stream,
                     word, W1p, aspc, Xlen, xproj);
  hipLaunchKernelGGL(k_rnn,    dim3(64),        dim3(256), 0, stream,
                     xproj, Whp, Xlen, hbuf, out);
}